// Round 1
// baseline (1122.325 us; speedup 1.0000x reference)
//
#include <hip/hip_runtime.h>
#include <stdint.h>

typedef __attribute__((ext_vector_type(8))) short bf16x8;
typedef __attribute__((ext_vector_type(4))) float f32x4;

__device__ __forceinline__ float bf2f(unsigned short b) {
  union { unsigned int u; float f; } c; c.u = ((unsigned int)b) << 16; return c.f;
}
__device__ __forceinline__ unsigned short f2bf(float f) {
  union { float f; unsigned int u; } c; c.f = f;
  unsigned int u = c.u;
  return (unsigned short)((u + 0x7fffu + ((u >> 16) & 1u)) >> 16);
}

__device__ __forceinline__ void gload_lds16(const void* g, void* l) {
  __builtin_amdgcn_global_load_lds((const __attribute__((address_space(1))) void*)g,
                                   (__attribute__((address_space(3))) void*)l,
                                   16, 0, 0);
}

// ---------------- convert / transpose ----------------

__global__ __launch_bounds__(256) void cvt_x(const float* __restrict__ in,
                                             unsigned short* __restrict__ out, int n4) {
  int i = blockIdx.x * 256 + threadIdx.x;
  if (i < n4) {
    float4 f = ((const float4*)in)[i];
    ushort4 o;
    o.x = f2bf(f.x); o.y = f2bf(f.y); o.z = f2bf(f.z); o.w = f2bf(f.w);
    ((ushort4*)out)[i] = o;
  }
}

// W [512][N] fp32  ->  Wt [N][512] bf16
__global__ __launch_bounds__(256) void tw_cvt(const float* __restrict__ W,
                                              unsigned short* __restrict__ Wt, int N) {
  int idx = blockIdx.x * 256 + threadIdx.x;  // < N*512
  int n = idx >> 9, k = idx & 511;
  Wt[idx] = f2bf(W[(size_t)k * N + n]);
}

// ---------------- bf16 MFMA GEMM:  C = A * Bt^T + bias ----------------
// A: [M][K] bf16 row-major.  Bt: [N][K] bf16 row-major (i.e. B transposed).
// QKV==1: scatter bf16 into q/k/v [B=2,H=8,S=4096,dh=64];  QKV==0: fp32 Cout.

template<int QKV>
__global__ __launch_bounds__(256)
void gemm_bt(const unsigned short* __restrict__ A, const unsigned short* __restrict__ Bt,
             const float* __restrict__ bias, float* __restrict__ Cout,
             unsigned short* __restrict__ qo, unsigned short* __restrict__ ko,
             unsigned short* __restrict__ vo, int M, int N, int K) {
  __shared__ unsigned short As[128 * 64];
  __shared__ unsigned short Bs[128 * 64];
  const int tid = threadIdx.x;
  const int wid = tid >> 6;
  const int lane = tid & 63;
  const int row0 = blockIdx.x * 128;
  const int col0 = blockIdx.y * 128;

  f32x4 acc[4][4];
#pragma unroll
  for (int m = 0; m < 4; ++m)
#pragma unroll
    for (int n = 0; n < 4; ++n)
      acc[m][n] = (f32x4){0.f, 0.f, 0.f, 0.f};

  const int wr = (wid >> 1) * 64;
  const int wc = (wid & 1) * 64;
  const int rw = lane & 15;
  const int nk = K >> 6;

  for (int kt = 0; kt < nk; ++kt) {
    const int k0 = kt << 6;
#pragma unroll
    for (int i = 0; i < 4; ++i) {
      int c = i * 256 + tid;
      int r = c >> 3, kq = (c & 7) << 3;
      gload_lds16(A + (size_t)(row0 + r) * K + k0 + kq, As + (size_t)(i * 256 + wid * 64) * 8);
    }
#pragma unroll
    for (int i = 0; i < 4; ++i) {
      int c = i * 256 + tid;
      int r = c >> 3, kq = (c & 7) << 3;
      gload_lds16(Bt + (size_t)(col0 + r) * K + k0 + kq, Bs + (size_t)(i * 256 + wid * 64) * 8);
    }
    __syncthreads();
#pragma unroll
    for (int ks = 0; ks < 2; ++ks) {
      const int kof = ks * 32 + (lane >> 4) * 8;
      bf16x8 af[4], bfr[4];
#pragma unroll
      for (int m = 0; m < 4; ++m)
        af[m] = *(const bf16x8*)&As[(wr + m * 16 + rw) * 64 + kof];
#pragma unroll
      for (int n = 0; n < 4; ++n)
        bfr[n] = *(const bf16x8*)&Bs[(wc + n * 16 + rw) * 64 + kof];
#pragma unroll
      for (int m = 0; m < 4; ++m)
#pragma unroll
        for (int n = 0; n < 4; ++n)
          acc[m][n] = __builtin_amdgcn_mfma_f32_16x16x32_bf16(af[m], bfr[n], acc[m][n], 0, 0, 0);
    }
    __syncthreads();
  }

  const int lr4 = (lane >> 4) * 4;
  const int lc = lane & 15;
#pragma unroll
  for (int m = 0; m < 4; ++m) {
#pragma unroll
    for (int n = 0; n < 4; ++n) {
      const int col = col0 + wc + n * 16 + lc;
      const float bb = bias[col];
#pragma unroll
      for (int r2 = 0; r2 < 4; ++r2) {
        const int row = row0 + wr + m * 16 + lr4 + r2;
        float val = acc[m][n][r2] + bb;
        if (QKV) {
          int which = col >> 9, rem = col & 511, h = rem >> 6, d = rem & 63;
          unsigned short* dst = which == 0 ? qo : (which == 1 ? ko : vo);
          int b = row >> 12, s = row & 4095;
          dst[(((size_t)(b * 8 + h) * 4096 + s) << 6) + d] = f2bf(val);
        } else {
          Cout[(size_t)row * N + col] = val;
        }
      }
    }
  }
}

// ---------------- flash attention (fp32 vector, causal) ----------------
// grid: (S/64, B*H).  block 256.  thread = (R,C): R=tid>>4 rows R*4..+4, C=tid&15.
// Score phase: C = key-block; PV phase: C = d-block.  16-lane row groups stay in
// one wave, so per-row softmax state reduces with shfl_xor 1/2/4/8 and the
// transposed P tile needs no barrier (wave-private columns).

__global__ __launch_bounds__(256)
void attn_fwd(const unsigned short* __restrict__ Qb, const unsigned short* __restrict__ Kb,
              const unsigned short* __restrict__ Vb, unsigned short* __restrict__ Ob,
              const int* __restrict__ causal_p) {
  __shared__ float QsT[64][68];  // [d][row], pre-scaled by 1/8
  __shared__ float KsT[64][68];  // [d][key]
  __shared__ float Vs[64][68];   // [key][d]
  __shared__ float PsT[64][68];  // [key][row]
  const int tid = threadIdx.x;
  const int R = tid >> 4;
  const int C = tid & 15;
  const int qi = blockIdx.x;
  const int bh = blockIdx.y;
  const int causal = *causal_p;
  const size_t base = (size_t)bh * 4096 * 64;

  for (int i = tid; i < 64 * 16; i += 256) {
    int j = i >> 4, d4 = (i & 15) * 4;
    ushort4 u = *(const ushort4*)(Qb + base + (size_t)(qi * 64 + j) * 64 + d4);
    QsT[d4 + 0][j] = bf2f(u.x) * 0.125f;
    QsT[d4 + 1][j] = bf2f(u.y) * 0.125f;
    QsT[d4 + 2][j] = bf2f(u.z) * 0.125f;
    QsT[d4 + 3][j] = bf2f(u.w) * 0.125f;
  }

  float m[4], l[4], acc[4][4];
#pragma unroll
  for (int ii = 0; ii < 4; ++ii) {
    m[ii] = -1e30f; l[ii] = 0.f;
#pragma unroll
    for (int dd = 0; dd < 4; ++dd) acc[ii][dd] = 0.f;
  }

  const int ktend = causal ? qi : 63;
  for (int kt = 0; kt <= ktend; ++kt) {
    __syncthreads();
    for (int i = tid; i < 64 * 16; i += 256) {
      int j = i >> 4, d4 = (i & 15) * 4;
      ushort4 u = *(const ushort4*)(Kb + base + (size_t)(kt * 64 + j) * 64 + d4);
      KsT[d4 + 0][j] = bf2f(u.x);
      KsT[d4 + 1][j] = bf2f(u.y);
      KsT[d4 + 2][j] = bf2f(u.z);
      KsT[d4 + 3][j] = bf2f(u.w);
      ushort4 w = *(const ushort4*)(Vb + base + (size_t)(kt * 64 + j) * 64 + d4);
      float4 vv;
      vv.x = bf2f(w.x); vv.y = bf2f(w.y); vv.z = bf2f(w.z); vv.w = bf2f(w.w);
      *(float4*)&Vs[j][d4] = vv;
    }
    __syncthreads();

    float s[4][4];
#pragma unroll
    for (int ii = 0; ii < 4; ++ii)
#pragma unroll
      for (int jj = 0; jj < 4; ++jj) s[ii][jj] = 0.f;

    for (int d = 0; d < 64; ++d) {
      float4 qv = *(const float4*)&QsT[d][R * 4];
      float4 kv = *(const float4*)&KsT[d][C * 4];
      float qa[4] = {qv.x, qv.y, qv.z, qv.w};
      float ka[4] = {kv.x, kv.y, kv.z, kv.w};
#pragma unroll
      for (int ii = 0; ii < 4; ++ii)
#pragma unroll
        for (int jj = 0; jj < 4; ++jj) s[ii][jj] += qa[ii] * ka[jj];
    }

    if (causal && kt == qi) {
#pragma unroll
      for (int ii = 0; ii < 4; ++ii)
#pragma unroll
        for (int jj = 0; jj < 4; ++jj)
          if (C * 4 + jj > R * 4 + ii) s[ii][jj] = -1e30f;
    }

#pragma unroll
    for (int ii = 0; ii < 4; ++ii) {
      float tm = fmaxf(fmaxf(s[ii][0], s[ii][1]), fmaxf(s[ii][2], s[ii][3]));
      tm = fmaxf(tm, __shfl_xor(tm, 1));
      tm = fmaxf(tm, __shfl_xor(tm, 2));
      tm = fmaxf(tm, __shfl_xor(tm, 4));
      tm = fmaxf(tm, __shfl_xor(tm, 8));
      float mn = fmaxf(m[ii], tm);
      float sc = __expf(m[ii] - mn);
      float ls = 0.f;
#pragma unroll
      for (int jj = 0; jj < 4; ++jj) {
        float p = __expf(s[ii][jj] - mn);
        s[ii][jj] = p;
        ls += p;
      }
      ls += __shfl_xor(ls, 1);
      ls += __shfl_xor(ls, 2);
      ls += __shfl_xor(ls, 4);
      ls += __shfl_xor(ls, 8);
      l[ii] = l[ii] * sc + ls;
      m[ii] = mn;
#pragma unroll
      for (int dd = 0; dd < 4; ++dd) acc[ii][dd] *= sc;
#pragma unroll
      for (int jj = 0; jj < 4; ++jj) PsT[C * 4 + jj][R * 4 + ii] = s[ii][jj];
    }

    for (int j = 0; j < 64; ++j) {
      float4 pv = *(const float4*)&PsT[j][R * 4];
      float4 vv = *(const float4*)&Vs[j][C * 4];
      float pa[4] = {pv.x, pv.y, pv.z, pv.w};
      float va[4] = {vv.x, vv.y, vv.z, vv.w};
#pragma unroll
      for (int ii = 0; ii < 4; ++ii)
#pragma unroll
        for (int dd = 0; dd < 4; ++dd) acc[ii][dd] += pa[ii] * va[dd];
    }
  }

  const int b = bh >> 3, h = bh & 7;
#pragma unroll
  for (int ii = 0; ii < 4; ++ii) {
    const int token = (b << 12) + qi * 64 + R * 4 + ii;
    const float inv = 1.0f / l[ii];
    ushort4 u;
    u.x = f2bf(acc[ii][0] * inv);
    u.y = f2bf(acc[ii][1] * inv);
    u.z = f2bf(acc[ii][2] * inv);
    u.w = f2bf(acc[ii][3] * inv);
    *(ushort4*)(Ob + (size_t)token * 512 + h * 64 + C * 4) = u;
  }
}

// ---------------- launch ----------------

extern "C" void kernel_launch(void* const* d_in, const int* in_sizes, int n_in,
                              void* d_out, int out_size, void* d_ws, size_t ws_size,
                              hipStream_t stream) {
  const float* x     = (const float*)d_in[0];
  const float* W_in  = (const float*)d_in[1];
  const float* b_in  = (const float*)d_in[2];
  const float* W_out = (const float*)d_in[3];
  const float* b_out = (const float*)d_in[4];
  const int* causal  = (const int*)d_in[5];
  float* out = (float*)d_out;

  unsigned short* xb   = (unsigned short*)d_ws;       // 8192*512  (also attn output later)
  unsigned short* wint = xb + 4194304;                // 1536*512
  unsigned short* wout = wint + 786432;               // 512*512
  unsigned short* qb   = wout + 262144;               // 16*4096*64
  unsigned short* kb   = qb + 4194304;
  unsigned short* vb   = kb + 4194304;

  cvt_x<<<4096, 256, 0, stream>>>(x, xb, 4194304 / 4);
  tw_cvt<<<3072, 256, 0, stream>>>(W_in, wint, 1536);
  tw_cvt<<<1024, 256, 0, stream>>>(W_out, wout, 512);

  gemm_bt<1><<<dim3(64, 12), 256, 0, stream>>>(xb, wint, b_in, nullptr, qb, kb, vb,
                                               8192, 1536, 512);

  attn_fwd<<<dim3(64, 16), 256, 0, stream>>>(qb, kb, vb, xb, causal);

  gemm_bt<0><<<dim3(64, 4), 256, 0, stream>>>(xb, wout, b_out, out, nullptr, nullptr, nullptr,
                                              8192, 512, 512);
}

// Round 2
// 347.942 us; speedup vs baseline: 3.2256x; 3.2256x over previous
//
#include <hip/hip_runtime.h>
#include <stdint.h>

typedef __attribute__((ext_vector_type(8))) short bf16x8;
typedef __attribute__((ext_vector_type(4))) float f32x4;

__device__ __forceinline__ float bf2f(unsigned short b) {
  union { unsigned int u; float f; } c; c.u = ((unsigned int)b) << 16; return c.f;
}
__device__ __forceinline__ unsigned short f2bf(float f) {
  union { float f; unsigned int u; } c; c.f = f;
  unsigned int u = c.u;
  return (unsigned short)((u + 0x7fffu + ((u >> 16) & 1u)) >> 16);
}

__device__ __forceinline__ void gload_lds16(const void* g, void* l) {
  __builtin_amdgcn_global_load_lds((const __attribute__((address_space(1))) void*)g,
                                   (__attribute__((address_space(3))) void*)l,
                                   16, 0, 0);
}

// ---------------- convert / transpose ----------------

__global__ __launch_bounds__(256) void cvt_x(const float* __restrict__ in,
                                             unsigned short* __restrict__ out, int n4) {
  int i = blockIdx.x * 256 + threadIdx.x;
  if (i < n4) {
    float4 f = ((const float4*)in)[i];
    ushort4 o;
    o.x = f2bf(f.x); o.y = f2bf(f.y); o.z = f2bf(f.z); o.w = f2bf(f.w);
    ((ushort4*)out)[i] = o;
  }
}

// W [512][N] fp32  ->  Wt [N][512] bf16
__global__ __launch_bounds__(256) void tw_cvt(const float* __restrict__ W,
                                              unsigned short* __restrict__ Wt, int N) {
  int idx = blockIdx.x * 256 + threadIdx.x;  // < N*512
  int n = idx >> 9, k = idx & 511;
  Wt[idx] = f2bf(W[(size_t)k * N + n]);
}

// ---------------- bf16 MFMA GEMM:  C = A * Bt^T + bias ----------------
// A: [M][K] bf16 row-major.  Bt: [N][K] bf16 row-major (B transposed).
// QKV==1: scatter into q [bh][s][64] (pre-scaled 1/8), k [bh][s][64],
//         v TRANSPOSED [bh][64][4096].   QKV==0: fp32 Cout += bias.

template<int QKV>
__global__ __launch_bounds__(256)
void gemm_bt(const unsigned short* __restrict__ A, const unsigned short* __restrict__ Bt,
             const float* __restrict__ bias, float* __restrict__ Cout,
             unsigned short* __restrict__ qo, unsigned short* __restrict__ ko,
             unsigned short* __restrict__ vo, int M, int N, int K) {
  __shared__ unsigned short As[128 * 64];
  __shared__ unsigned short Bs[128 * 64];
  const int tid = threadIdx.x;
  const int wid = tid >> 6;
  const int lane = tid & 63;
  const int row0 = blockIdx.x * 128;
  const int col0 = blockIdx.y * 128;

  f32x4 acc[4][4];
#pragma unroll
  for (int m = 0; m < 4; ++m)
#pragma unroll
    for (int n = 0; n < 4; ++n)
      acc[m][n] = (f32x4){0.f, 0.f, 0.f, 0.f};

  const int wr = (wid >> 1) * 64;
  const int wc = (wid & 1) * 64;
  const int rw = lane & 15;
  const int nk = K >> 6;

  for (int kt = 0; kt < nk; ++kt) {
    const int k0 = kt << 6;
#pragma unroll
    for (int i = 0; i < 4; ++i) {
      int c = i * 256 + tid;
      int r = c >> 3, kq = (c & 7) << 3;
      gload_lds16(A + (size_t)(row0 + r) * K + k0 + kq, As + (size_t)(i * 256 + wid * 64) * 8);
    }
#pragma unroll
    for (int i = 0; i < 4; ++i) {
      int c = i * 256 + tid;
      int r = c >> 3, kq = (c & 7) << 3;
      gload_lds16(Bt + (size_t)(col0 + r) * K + k0 + kq, Bs + (size_t)(i * 256 + wid * 64) * 8);
    }
    __syncthreads();
#pragma unroll
    for (int ks = 0; ks < 2; ++ks) {
      const int kof = ks * 32 + (lane >> 4) * 8;
      bf16x8 af[4], bfr[4];
#pragma unroll
      for (int m = 0; m < 4; ++m)
        af[m] = *(const bf16x8*)&As[(wr + m * 16 + rw) * 64 + kof];
#pragma unroll
      for (int n = 0; n < 4; ++n)
        bfr[n] = *(const bf16x8*)&Bs[(wc + n * 16 + rw) * 64 + kof];
#pragma unroll
      for (int m = 0; m < 4; ++m)
#pragma unroll
        for (int n = 0; n < 4; ++n)
          acc[m][n] = __builtin_amdgcn_mfma_f32_16x16x32_bf16(af[m], bfr[n], acc[m][n], 0, 0, 0);
    }
    __syncthreads();
  }

  const int lr4 = (lane >> 4) * 4;
  const int lc = lane & 15;
#pragma unroll
  for (int m = 0; m < 4; ++m) {
#pragma unroll
    for (int n = 0; n < 4; ++n) {
      const int col = col0 + wc + n * 16 + lc;
      const float bb = bias[col];
      const int row = row0 + wr + m * 16 + lr4;
      if (QKV) {
        const int which = col >> 9;
        const int rem = col & 511, h = rem >> 6, d = rem & 63;
        const int b = row >> 12, s = row & 4095;
        if (which == 2) {
          ushort4 u;
          u.x = f2bf(acc[m][n][0] + bb);
          u.y = f2bf(acc[m][n][1] + bb);
          u.z = f2bf(acc[m][n][2] + bb);
          u.w = f2bf(acc[m][n][3] + bb);
          *(ushort4*)&vo[(((size_t)(b * 8 + h) * 64 + d) << 12) + s] = u;
        } else {
          const float scale = (which == 0) ? 0.125f : 1.0f;
          unsigned short* dst = (which == 0) ? qo : ko;
#pragma unroll
          for (int r2 = 0; r2 < 4; ++r2)
            dst[(((size_t)(b * 8 + h) * 4096 + (s + r2)) << 6) + d] =
                f2bf((acc[m][n][r2] + bb) * scale);
        }
      } else {
#pragma unroll
        for (int r2 = 0; r2 < 4; ++r2)
          Cout[(size_t)(row + r2) * N + col] = acc[m][n][r2] + bb;
      }
    }
  }
}

// ---------------- MFMA flash attention (bf16, causal) ----------------
// grid (16, BH). 512 threads = 8 waves. Waves 0-3: q-tile p, waves 4-7:
// q-tile 31-p (causal work balance: per-SIMD wave pair does 66 kv-tiles).
// Each wave owns 32 q rows. KV tile = 64. All LDS tiles XOR-swizzled
// (byte ^= (row&7)<<4) for conflict-free ds_read_b128; staging pre-swizzles
// the GLOBAL source so global_load_lds's linear dest lands swizzled.

__global__ __launch_bounds__(512, 2)
void attn_mfma(const unsigned short* __restrict__ Qb, const unsigned short* __restrict__ Kb,
               const unsigned short* __restrict__ Vtb, unsigned short* __restrict__ Ob,
               const int* __restrict__ causal_p) {
  __shared__ unsigned short Qs[256 * 64];    // rows 0-127: tile A, 128-255: tile B
  __shared__ unsigned short Ks[64 * 64];     // [key][d]
  __shared__ unsigned short Vs[64 * 64];     // [d][key]   (from v^T global)
  __shared__ unsigned short Ps[8][32 * 64];  // per-wave P, swizzled

  const int tid = threadIdx.x;
  const int wid = tid >> 6;
  const int lane = tid & 63;
  const int lx = lane & 15, ly = lane >> 4, l7 = lane & 7;
  const int p = blockIdx.x;
  const int bh = blockIdx.y;
  const int causal = *causal_p;
  const int qtile = (wid < 4) ? p : (31 - p);
  const int qw = qtile * 128 + (wid & 3) * 32;   // this wave's global q base
  const int qldsb = ((wid < 4) ? 0 : 128) + (wid & 3) * 32;
  const size_t qkbase = (size_t)bh * 4096 * 64;
  const size_t vbase = (size_t)bh * 64 * 4096;

  // ---- stage Q (both tiles), swizzled source ----
  {
    const int pa = p, pb = 31 - p;
#pragma unroll
    for (int i = 0; i < 4; ++i) {
      int c = i * 512 + tid;               // 16B-chunk index, 0..2047
      int r = c >> 3, ch = c & 7;
      int qrow = (r < 128) ? (pa * 128 + r) : (pb * 128 + (r - 128));
      gload_lds16(Qb + qkbase + (size_t)qrow * 64 + ((ch ^ (r & 7)) << 3),
                  Qs + (size_t)(i * 512 + wid * 64) * 8);
    }
  }

  f32x4 o[2][4];
  float mrow[2][4], lrow[2][4];
#pragma unroll
  for (int rf = 0; rf < 2; ++rf) {
#pragma unroll
    for (int df = 0; df < 4; ++df) o[rf][df] = (f32x4){0.f, 0.f, 0.f, 0.f};
#pragma unroll
    for (int r = 0; r < 4; ++r) { mrow[rf][r] = -1e30f; lrow[rf][r] = 0.f; }
  }

  const int ktmax = causal ? (63 - 2 * p) : 63;
  for (int kt = 0; kt <= ktmax; ++kt) {
    __syncthreads();   // previous tile's readers done (also Q-stage fence at kt=0)
    {
      int r = tid >> 3, ch = tid & 7;      // 512 chunks each for K and V^T
      gload_lds16(Kb + qkbase + (size_t)(kt * 64 + r) * 64 + ((ch ^ (r & 7)) << 3),
                  Ks + (size_t)(wid * 64) * 8);
      gload_lds16(Vtb + vbase + (size_t)r * 4096 + kt * 64 + ((ch ^ (r & 7)) << 3),
                  Vs + (size_t)(wid * 64) * 8);
    }
    __syncthreads();   // staging drained (compiler emits vmcnt(0) before barrier)

    const int ktb = kt * 64;
    if (!causal || ktb <= qw + 31) {
      // ---- QK^T: S[32q][64k] ----
      f32x4 s[2][4];
#pragma unroll
      for (int rf = 0; rf < 2; ++rf)
#pragma unroll
        for (int cf = 0; cf < 4; ++cf) s[rf][cf] = (f32x4){0.f, 0.f, 0.f, 0.f};
#pragma unroll
      for (int ks = 0; ks < 2; ++ks) {
        const int kel = ((ks * 4 + ly) ^ l7) << 3;   // swizzled element offset
        bf16x8 a[2], bb[4];
#pragma unroll
        for (int rf = 0; rf < 2; ++rf)
          a[rf] = *(const bf16x8*)&Qs[(qldsb + rf * 16 + lx) * 64 + kel];
#pragma unroll
        for (int cf = 0; cf < 4; ++cf)
          bb[cf] = *(const bf16x8*)&Ks[(cf * 16 + lx) * 64 + kel];
#pragma unroll
        for (int rf = 0; rf < 2; ++rf)
#pragma unroll
          for (int cf = 0; cf < 4; ++cf)
            s[rf][cf] = __builtin_amdgcn_mfma_f32_16x16x32_bf16(a[rf], bb[cf], s[rf][cf], 0, 0, 0);
      }

      const bool diag = causal && (ktb + 63 > qw);
      // ---- online softmax + P write ----
#pragma unroll
      for (int rf = 0; rf < 2; ++rf) {
#pragma unroll
        for (int r = 0; r < 4; ++r) {
          const int qg = qw + rf * 16 + ly * 4 + r;
          if (diag) {
#pragma unroll
            for (int cf = 0; cf < 4; ++cf)
              if (ktb + cf * 16 + lx > qg) s[rf][cf][r] = -1e30f;
          }
          float tm = fmaxf(fmaxf(s[rf][0][r], s[rf][1][r]), fmaxf(s[rf][2][r], s[rf][3][r]));
          tm = fmaxf(tm, __shfl_xor(tm, 1));
          tm = fmaxf(tm, __shfl_xor(tm, 2));
          tm = fmaxf(tm, __shfl_xor(tm, 4));
          tm = fmaxf(tm, __shfl_xor(tm, 8));
          const float mo = mrow[rf][r];
          const float mn = fmaxf(mo, tm);
          const float scl = __expf(mo - mn);
          float ls = 0.f;
          const int ql = rf * 16 + ly * 4 + r;
          const int swz = (ql & 7) << 3;
#pragma unroll
          for (int cf = 0; cf < 4; ++cf) {
            float pv = __expf(s[rf][cf][r] - mn);
            ls += pv;
            Ps[wid][ql * 64 + ((cf * 16 + lx) ^ swz)] = f2bf(pv);
          }
          ls += __shfl_xor(ls, 1);
          ls += __shfl_xor(ls, 2);
          ls += __shfl_xor(ls, 4);
          ls += __shfl_xor(ls, 8);
          lrow[rf][r] = lrow[rf][r] * scl + ls;
          mrow[rf][r] = mn;
#pragma unroll
          for (int df = 0; df < 4; ++df) o[rf][df][r] *= scl;
        }
      }

      // ---- PV: O += P * V ----
#pragma unroll
      for (int ks = 0; ks < 2; ++ks) {
        const int kel = ((ks * 4 + ly) ^ l7) << 3;
        bf16x8 pa[2], vb_[4];
#pragma unroll
        for (int rf = 0; rf < 2; ++rf)
          pa[rf] = *(const bf16x8*)&Ps[wid][(rf * 16 + lx) * 64 + kel];
#pragma unroll
        for (int df = 0; df < 4; ++df)
          vb_[df] = *(const bf16x8*)&Vs[(df * 16 + lx) * 64 + kel];
#pragma unroll
        for (int rf = 0; rf < 2; ++rf)
#pragma unroll
          for (int df = 0; df < 4; ++df)
            o[rf][df] = __builtin_amdgcn_mfma_f32_16x16x32_bf16(pa[rf], vb_[df], o[rf][df], 0, 0, 0);
      }
    }
  }

  // ---- epilogue ----
  const int b = bh >> 3, h = bh & 7;
#pragma unroll
  for (int rf = 0; rf < 2; ++rf) {
#pragma unroll
    for (int r = 0; r < 4; ++r) {
      const float inv = 1.0f / lrow[rf][r];
      const int row = b * 4096 + qw + rf * 16 + ly * 4 + r;
#pragma unroll
      for (int df = 0; df < 4; ++df)
        Ob[(size_t)row * 512 + h * 64 + df * 16 + lx] = f2bf(o[rf][df][r] * inv);
    }
  }
}

// ---------------- launch ----------------

extern "C" void kernel_launch(void* const* d_in, const int* in_sizes, int n_in,
                              void* d_out, int out_size, void* d_ws, size_t ws_size,
                              hipStream_t stream) {
  const float* x     = (const float*)d_in[0];
  const float* W_in  = (const float*)d_in[1];
  const float* b_in  = (const float*)d_in[2];
  const float* W_out = (const float*)d_in[3];
  const float* b_out = (const float*)d_in[4];
  const int* causal  = (const int*)d_in[5];
  float* out = (float*)d_out;

  unsigned short* xb   = (unsigned short*)d_ws;       // 8192*512 bf16 x; later attn out
  unsigned short* wint = xb + 4194304;                // 1536*512
  unsigned short* wout = wint + 786432;               // 512*512
  unsigned short* qb   = wout + 262144;               // [16][4096][64]
  unsigned short* kb   = qb + 4194304;                // [16][4096][64]
  unsigned short* vt   = kb + 4194304;                // [16][64][4096]  (v transposed)

  cvt_x<<<4096, 256, 0, stream>>>(x, xb, 4194304 / 4);
  tw_cvt<<<3072, 256, 0, stream>>>(W_in, wint, 1536);
  tw_cvt<<<1024, 256, 0, stream>>>(W_out, wout, 512);

  gemm_bt<1><<<dim3(64, 12), 256, 0, stream>>>(xb, wint, b_in, nullptr, qb, kb, vt,
                                               8192, 1536, 512);

  attn_mfma<<<dim3(16, 16), 512, 0, stream>>>(qb, kb, vt, xb, causal);

  gemm_bt<0><<<dim3(64, 4), 256, 0, stream>>>(xb, wout, b_out, out, nullptr, nullptr, nullptr,
                                              8192, 512, 512);
}